// Round 3
// baseline (952.007 us; speedup 1.0000x reference)
//
#include <hip/hip_runtime.h>

// dv = (-v + segment_sum(w * relu(v[src]) * tp[ntype[src]], dst) + stim + Vrest) / tau
// N_NODES = 500000, N_EDGES = 16000000. edge_index flat: src=[0,E), dst=[E,2E).
//
// Round-1: agent-scope fp32 atomics -> memory-side RMW wall (~20G/s) -> 785us.
// Round-2: counting sort -> 16M uncoalesced 4B writes, 7x write amplification -> 489us.
// Round-3 idea: per-XCD privatized accumulators + WORKGROUP-scope atomics.
//   Workgroup scope lets the atomic execute in the local XCD's TCC (L2) instead
//   of at the device-wide point of coherence. Copy c is only touched by blocks
//   physically on XCD c (HW_REG_XCC_ID), so single-L2 residency is guaranteed;
//   kernel-boundary release fences publish the copies to the reduce kernel.
//   Each copy (2MB) + g (2MB) fits one XCD's 4MB L2.

#define NXCD 8

__device__ __forceinline__ unsigned xcc_id() {
    unsigned x;
    asm volatile("s_getreg_b32 %0, hwreg(HW_REG_XCC_ID)" : "=s"(x));
    return x & (NXCD - 1);
}

// g[i] = relu(v[i]) * tp[ntype[i]]; zero the NXCD accumulator copies (ws is
// poisoned 0xAA before every launch).
__global__ void pre_kernel(const float* __restrict__ v,
                           const int* __restrict__ ntype,
                           const float* __restrict__ tp,
                           float* __restrict__ g,
                           float* __restrict__ copies,
                           int n_nodes) {
    int i = blockIdx.x * blockDim.x + threadIdx.x;
    if (i < n_nodes) {
        float x = v[i];
        x = x > 0.0f ? x : 0.0f;
        g[i] = x * tp[ntype[i]];
    }
    int total = NXCD * n_nodes;
    int total4 = total >> 2;
    float4 z = make_float4(0.f, 0.f, 0.f, 0.f);
    int stride = gridDim.x * blockDim.x;
    for (int j = i; j < total4; j += stride) ((float4*)copies)[j] = z;
    if (i < (total & 3)) copies[total4 * 4 + i] = 0.0f;
}

__global__ void edge_kernel(const int* __restrict__ src,
                            const int* __restrict__ dst,
                            const float* __restrict__ w,
                            const float* __restrict__ g,
                            float* __restrict__ copies,
                            int n_nodes, int G) {
    float* msg = copies + (size_t)xcc_id() * n_nodes;
    int i = blockIdx.x * blockDim.x + threadIdx.x;
    if (i < G) {
        int4   s  = ((const int4*)src)[i];
        int4   d  = ((const int4*)dst)[i];
        float4 wv = ((const float4*)w)[i];
        __hip_atomic_fetch_add(&msg[d.x], wv.x * g[s.x],
                               __ATOMIC_RELAXED, __HIP_MEMORY_SCOPE_WORKGROUP);
        __hip_atomic_fetch_add(&msg[d.y], wv.y * g[s.y],
                               __ATOMIC_RELAXED, __HIP_MEMORY_SCOPE_WORKGROUP);
        __hip_atomic_fetch_add(&msg[d.z], wv.z * g[s.z],
                               __ATOMIC_RELAXED, __HIP_MEMORY_SCOPE_WORKGROUP);
        __hip_atomic_fetch_add(&msg[d.w], wv.w * g[s.w],
                               __ATOMIC_RELAXED, __HIP_MEMORY_SCOPE_WORKGROUP);
    }
}

__global__ void edge_tail_kernel(const int* __restrict__ src,
                                 const int* __restrict__ dst,
                                 const float* __restrict__ w,
                                 const float* __restrict__ g,
                                 float* __restrict__ copies,
                                 int n_nodes, int start, int n_edges) {
    float* msg = copies + (size_t)xcc_id() * n_nodes;
    int i = start + blockIdx.x * blockDim.x + threadIdx.x;
    if (i < n_edges)
        __hip_atomic_fetch_add(&msg[dst[i]], w[i] * g[src[i]],
                               __ATOMIC_RELAXED, __HIP_MEMORY_SCOPE_WORKGROUP);
}

// out = (-v + sum_c copies[c] + stim + vrest) / tau, float4-vectorized.
__global__ void reduce_kernel(const float* __restrict__ v,
                              const float* __restrict__ stim,
                              const float* __restrict__ vrest,
                              const float* __restrict__ tau,
                              const float* __restrict__ copies,
                              float* __restrict__ out,
                              int n_nodes) {
    int i = blockIdx.x * blockDim.x + threadIdx.x;
    int n4 = n_nodes >> 2;
    if (i < n4) {
        float4 s = ((const float4*)copies)[i];
        #pragma unroll
        for (int c = 1; c < NXCD; c++) {
            float4 t = ((const float4*)(copies + (size_t)c * n_nodes))[i];
            s.x += t.x; s.y += t.y; s.z += t.z; s.w += t.w;
        }
        float4 vv = ((const float4*)v)[i];
        float4 st = ((const float4*)stim)[i];
        float4 vr = ((const float4*)vrest)[i];
        float4 tu = ((const float4*)tau)[i];
        float4 o;
        o.x = (-vv.x + s.x + st.x + vr.x) / tu.x;
        o.y = (-vv.y + s.y + st.y + vr.y) / tu.y;
        o.z = (-vv.z + s.z + st.z + vr.z) / tu.z;
        o.w = (-vv.w + s.w + st.w + vr.w) / tu.w;
        ((float4*)out)[i] = o;
    } else {
        int j = n4 * 4 + (i - n4);
        if (j < n_nodes) {
            float s = 0.0f;
            #pragma unroll
            for (int c = 0; c < NXCD; c++) s += copies[(size_t)c * n_nodes + j];
            out[j] = (-v[j] + s + stim[j] + vrest[j]) / tau[j];
        }
    }
}

// ---------------- fallback (agent-scope atomics, always correct) ----------------

__global__ void node_pre_kernel(const float* __restrict__ v,
                                const int* __restrict__ ntype,
                                const float* __restrict__ tp,
                                float* __restrict__ g,
                                float* __restrict__ msg, int n) {
    int i = blockIdx.x * blockDim.x + threadIdx.x;
    if (i < n) {
        float x = v[i];
        x = x > 0.0f ? x : 0.0f;
        g[i] = x * tp[ntype[i]];
        msg[i] = 0.0f;
    }
}

__global__ void edge_scatter_kernel(const int* __restrict__ src,
                                    const int* __restrict__ dst,
                                    const float* __restrict__ w,
                                    const float* __restrict__ g,
                                    float* __restrict__ msg, int n_vec) {
    int i = blockIdx.x * blockDim.x + threadIdx.x;
    if (i < n_vec) {
        int4 s = ((const int4*)src)[i];
        int4 d = ((const int4*)dst)[i];
        float4 wv = ((const float4*)w)[i];
        atomicAdd(&msg[d.x], wv.x * g[s.x]);
        atomicAdd(&msg[d.y], wv.y * g[s.y]);
        atomicAdd(&msg[d.z], wv.z * g[s.z]);
        atomicAdd(&msg[d.w], wv.w * g[s.w]);
    }
}

__global__ void edge_scatter_tail(const int* __restrict__ src,
                                  const int* __restrict__ dst,
                                  const float* __restrict__ w,
                                  const float* __restrict__ g,
                                  float* __restrict__ msg,
                                  int start, int n_edges) {
    int i = start + blockIdx.x * blockDim.x + threadIdx.x;
    if (i < n_edges) atomicAdd(&msg[dst[i]], w[i] * g[src[i]]);
}

__global__ void node_post_kernel(const float* __restrict__ v,
                                 const float* __restrict__ msg,
                                 const float* __restrict__ stim,
                                 const float* __restrict__ vrest,
                                 const float* __restrict__ tau,
                                 float* __restrict__ out, int n) {
    int i = blockIdx.x * blockDim.x + threadIdx.x;
    if (i < n)
        out[i] = (-v[i] + msg[i] + stim[i] + vrest[i]) / tau[i];
}

// ---------------- launch ----------------

extern "C" void kernel_launch(void* const* d_in, const int* in_sizes, int n_in,
                              void* d_out, int out_size, void* d_ws, size_t ws_size,
                              hipStream_t stream) {
    const float* voltage  = (const float*)d_in[0];
    const float* stimulus = (const float*)d_in[1];
    const int*   ntype    = (const int*)d_in[2];
    const int*   edge_idx = (const int*)d_in[3];
    const float* w        = (const float*)d_in[4];
    const float* vrest    = (const float*)d_in[5];
    const float* tau      = (const float*)d_in[6];
    const float* tp       = (const float*)d_in[7];
    float* out = (float*)d_out;

    const int n_nodes = in_sizes[0];
    const int n_edges = in_sizes[4];
    const int* src = edge_idx;
    const int* dst = edge_idx + n_edges;

    const int B = 256;
    const int G = n_edges / 4;

    auto align256 = [](size_t x) { return (x + 255) & ~(size_t)255; };
    size_t g_off      = 0;
    size_t copies_off = align256((size_t)n_nodes * 4);
    size_t need       = copies_off + (size_t)NXCD * n_nodes * 4;

    if (ws_size >= need) {
        float* g      = (float*)((char*)d_ws + g_off);
        float* copies = (float*)((char*)d_ws + copies_off);

        pre_kernel<<<(n_nodes + B - 1) / B, B, 0, stream>>>(
            voltage, ntype, tp, g, copies, n_nodes);

        if (G > 0)
            edge_kernel<<<(G + B - 1) / B, B, 0, stream>>>(
                src, dst, w, g, copies, n_nodes, G);
        if (G * 4 < n_edges) {
            int rem = n_edges - G * 4;
            edge_tail_kernel<<<(rem + B - 1) / B, B, 0, stream>>>(
                src, dst, w, g, copies, n_nodes, G * 4, n_edges);
        }

        int n4 = n_nodes >> 2;
        int nthreads = n4 + (n_nodes & 3);
        reduce_kernel<<<(nthreads + B - 1) / B, B, 0, stream>>>(
            voltage, stimulus, vrest, tau, copies, out, n_nodes);
    } else {
        float* g   = (float*)d_ws;
        float* msg = (float*)d_ws + n_nodes;
        node_pre_kernel<<<(n_nodes + B - 1) / B, B, 0, stream>>>(
            voltage, ntype, tp, g, msg, n_nodes);
        if (G > 0)
            edge_scatter_kernel<<<(G + B - 1) / B, B, 0, stream>>>(
                src, dst, w, g, msg, G);
        if (G * 4 < n_edges) {
            int rem = n_edges - G * 4;
            edge_scatter_tail<<<(rem + B - 1) / B, B, 0, stream>>>(
                src, dst, w, g, msg, G * 4, n_edges);
        }
        node_post_kernel<<<(n_nodes + B - 1) / B, B, 0, stream>>>(
            voltage, msg, stimulus, vrest, tau, out, n_nodes);
    }
}

// Round 4
// 521.191 us; speedup vs baseline: 1.8266x; 1.8266x over previous
//
#include <hip/hip_runtime.h>

// dv = (-v + segment_sum(w * relu(v[src]) * tp[ntype[src]], dst) + stim + Vrest) / tau
// N_NODES = 500000, N_EDGES = 16000000. edge_index flat: src=[0,E), dst=[E,2E).
//
// R1: agent-scope fp32 atomics -> memory-side RMW wall (~20G/s) -> 785us.
// R2: counting sort, direct 4B random writes -> 7x write amp, 489us scatter.
// R3: workgroup-scope atomics == agent-scope (identical counters) -> scope
//     annotation does NOT relocate fp32 global atomics on gfx950.
// R4 (this): R2's deterministic sort, but scatter stages records in LDS
//     ordered by bucket and copies each bucket segment out as a contiguous
//     coalesced burst. Accum reads per-bucket contiguous ranges.

#define BSHIFT 9
#define BSIZE  512               // nodes per bucket
#define NBMAX  1024              // >= nb = ceil(500000/512) = 977
#define GPB    4096              // int4 groups per scatter block = 16384 edges
#define EPB    (GPB * 4)

// ---------------- main path ----------------

__global__ void pre_g_kernel(const float* __restrict__ v,
                             const int* __restrict__ ntype,
                             const float* __restrict__ tp,
                             float* __restrict__ g, int n) {
    int i = blockIdx.x * blockDim.x + threadIdx.x;
    if (i < n) {
        float x = v[i];
        x = x > 0.0f ? x : 0.0f;
        g[i] = x * tp[ntype[i]];
    }
}

__global__ void hist_kernel(const int* __restrict__ dst,
                            unsigned* __restrict__ cnt,
                            int G, int n_edges, int nblk, int nb) {
    __shared__ unsigned hist[NBMAX];
    int blk = blockIdx.x, tid = threadIdx.x;
    for (int i = tid; i < NBMAX; i += 256) hist[i] = 0;
    __syncthreads();
    const int4* d4 = (const int4*)dst;
    int gstart = blk * GPB;
    int gend = gstart + GPB; if (gend > G) gend = G;
    for (int i = gstart + tid; i < gend; i += 256) {
        int4 d = d4[i];
        atomicAdd(&hist[((unsigned)d.x) >> BSHIFT], 1u);
        atomicAdd(&hist[((unsigned)d.y) >> BSHIFT], 1u);
        atomicAdd(&hist[((unsigned)d.z) >> BSHIFT], 1u);
        atomicAdd(&hist[((unsigned)d.w) >> BSHIFT], 1u);
    }
    if (blk == nblk - 1) {
        for (int i = G * 4 + tid; i < n_edges; i += 256)
            atomicAdd(&hist[((unsigned)dst[i]) >> BSHIFT], 1u);
    }
    __syncthreads();
    for (int b = tid; b < nb; b += 256)
        cnt[(size_t)b * nblk + blk] = hist[b];
}

// grid = nb; row b of cnt -> exclusive prefix across blocks, total[b] = sum.
__global__ void scan_blocks_kernel(unsigned* __restrict__ cnt,
                                   unsigned* __restrict__ total, int nblk) {
    __shared__ unsigned buf[256];
    __shared__ unsigned carry;
    int b = blockIdx.x, tid = threadIdx.x;
    if (tid == 0) carry = 0;
    __syncthreads();
    unsigned* row = cnt + (size_t)b * nblk;
    for (int i0 = 0; i0 < nblk; i0 += 256) {
        int i = i0 + tid;
        unsigned v = (i < nblk) ? row[i] : 0u;
        buf[tid] = v;
        __syncthreads();
        for (int o = 1; o < 256; o <<= 1) {
            unsigned t = (tid >= o) ? buf[tid - o] : 0u;
            __syncthreads();
            buf[tid] += t;
            __syncthreads();
        }
        unsigned excl = buf[tid] - v;
        if (i < nblk) row[i] = carry + excl;
        __syncthreads();
        if (tid == 255) carry += buf[255];
        __syncthreads();
    }
    if (tid == 0) total[b] = carry;
}

// single block: exclusive scan of total[0..nb) -> base[0..nb)
__global__ void scan_buckets_kernel(const unsigned* __restrict__ total,
                                    unsigned* __restrict__ base, int nb) {
    __shared__ unsigned buf[256];
    int tid = threadIdx.x;
    unsigned v[4];
    unsigned s = 0;
    for (int k = 0; k < 4; k++) {
        int i = tid * 4 + k;
        v[k] = (i < nb) ? total[i] : 0u;
        s += v[k];
    }
    buf[tid] = s;
    __syncthreads();
    for (int o = 1; o < 256; o <<= 1) {
        unsigned t = (tid >= o) ? buf[tid - o] : 0u;
        __syncthreads();
        buf[tid] += t;
        __syncthreads();
    }
    unsigned run = buf[tid] - s;
    for (int k = 0; k < 4; k++) {
        int i = tid * 4 + k;
        if (i < nb) base[i] = run;
        run += v[k];
    }
}

// grid = nblk. Bin 16K edges into a bucket-ordered LDS staging buffer, then
// copy each bucket segment to its global slice as a coalesced burst.
__global__ void scatter_kernel(const int* __restrict__ src,
                               const int* __restrict__ dst,
                               const float* __restrict__ w,
                               const float* __restrict__ g,
                               const unsigned* __restrict__ base,
                               const unsigned* __restrict__ cnt,
                               unsigned* __restrict__ sorted,
                               int G, int n_edges, int nblk, int nb) {
    __shared__ unsigned stage[EPB];      // 64 KB
    __shared__ unsigned lcur[NBMAX];     // counts -> excl starts -> ends
    __shared__ unsigned gseg[NBMAX];     // global start of (bucket, this blk)
    __shared__ unsigned sbuf[256];
    int blk = blockIdx.x, tid = threadIdx.x;
    bool last = (blk == nblk - 1);

    for (int b = tid; b < NBMAX; b += 256) lcur[b] = 0;
    __syncthreads();

    const int4*   d4 = (const int4*)dst;
    const int4*   s4 = (const int4*)src;
    const float4* w4 = (const float4*)w;
    int gstart = blk * GPB;
    int gend = gstart + GPB; if (gend > G) gend = G;

    // pass 1: local histogram
    for (int i = gstart + tid; i < gend; i += 256) {
        int4 d = d4[i];
        atomicAdd(&lcur[((unsigned)d.x) >> BSHIFT], 1u);
        atomicAdd(&lcur[((unsigned)d.y) >> BSHIFT], 1u);
        atomicAdd(&lcur[((unsigned)d.z) >> BSHIFT], 1u);
        atomicAdd(&lcur[((unsigned)d.w) >> BSHIFT], 1u);
    }
    if (last) {
        for (int i = G * 4 + tid; i < n_edges; i += 256)
            atomicAdd(&lcur[((unsigned)dst[i]) >> BSHIFT], 1u);
    }
    __syncthreads();

    // local exclusive scan over NBMAX buckets (thread t owns t*4..t*4+3);
    // also fetch this block's global segment starts.
    unsigned v[4], ssum = 0;
    for (int k = 0; k < 4; k++) {
        v[k] = lcur[tid * 4 + k];
        ssum += v[k];
    }
    sbuf[tid] = ssum;
    __syncthreads();
    for (int o = 1; o < 256; o <<= 1) {
        unsigned t = (tid >= o) ? sbuf[tid - o] : 0u;
        __syncthreads();
        sbuf[tid] += t;
        __syncthreads();
    }
    unsigned run = sbuf[tid] - ssum;
    for (int k = 0; k < 4; k++) {
        int idx = tid * 4 + k;
        gseg[idx] = (idx < nb) ? base[idx] + cnt[(size_t)idx * nblk + blk] : 0u;
        lcur[idx] = run;
        run += v[k];
    }
    __syncthreads();

    // pass 2: bin packed records into LDS (value mantissa-high | local dst)
    for (int i = gstart + tid; i < gend; i += 256) {
        int4 s = s4[i]; int4 d = d4[i]; float4 wv = w4[i];
        {
            unsigned b = ((unsigned)d.x) >> BSHIFT;
            unsigned pos = atomicAdd(&lcur[b], 1u);
            stage[pos] = (__float_as_uint(wv.x * g[s.x]) & ~(unsigned)(BSIZE - 1)) |
                         ((unsigned)d.x & (BSIZE - 1));
        }
        {
            unsigned b = ((unsigned)d.y) >> BSHIFT;
            unsigned pos = atomicAdd(&lcur[b], 1u);
            stage[pos] = (__float_as_uint(wv.y * g[s.y]) & ~(unsigned)(BSIZE - 1)) |
                         ((unsigned)d.y & (BSIZE - 1));
        }
        {
            unsigned b = ((unsigned)d.z) >> BSHIFT;
            unsigned pos = atomicAdd(&lcur[b], 1u);
            stage[pos] = (__float_as_uint(wv.z * g[s.z]) & ~(unsigned)(BSIZE - 1)) |
                         ((unsigned)d.z & (BSIZE - 1));
        }
        {
            unsigned b = ((unsigned)d.w) >> BSHIFT;
            unsigned pos = atomicAdd(&lcur[b], 1u);
            stage[pos] = (__float_as_uint(wv.w * g[s.w]) & ~(unsigned)(BSIZE - 1)) |
                         ((unsigned)d.w & (BSIZE - 1));
        }
    }
    if (last) {
        for (int i = G * 4 + tid; i < n_edges; i += 256) {
            int dd = dst[i];
            unsigned b = ((unsigned)dd) >> BSHIFT;
            unsigned pos = atomicAdd(&lcur[b], 1u);
            stage[pos] = (__float_as_uint(w[i] * g[src[i]]) & ~(unsigned)(BSIZE - 1)) |
                         ((unsigned)dd & (BSIZE - 1));
        }
    }
    __syncthreads();

    // copy-out: one wave per bucket segment, coalesced global burst.
    // after pass 2, lcur[b] = segment end; start = (b ? lcur[b-1] : 0).
    int wave = tid >> 6, lane = tid & 63;
    for (int b = wave; b < nb; b += 4) {
        unsigned lend = lcur[b];
        unsigned lstart = (b == 0) ? 0u : lcur[b - 1];
        unsigned gs = gseg[b];
        for (unsigned j = lane; j < lend - lstart; j += 64)
            sorted[gs + j] = stage[lstart + j];
    }
}

// grid = nb; accumulate one bucket (contiguous record range) in LDS + epilogue.
__global__ void accum_kernel(const unsigned* __restrict__ sorted,
                             const unsigned* __restrict__ base,
                             const unsigned* __restrict__ total,
                             const float* __restrict__ v,
                             const float* __restrict__ stim,
                             const float* __restrict__ vrest,
                             const float* __restrict__ tau,
                             float* __restrict__ out,
                             int n_nodes) {
    __shared__ float acc[BSIZE];
    int b = blockIdx.x, tid = threadIdx.x;
    acc[tid] = 0.0f;
    acc[tid + 256] = 0.0f;
    __syncthreads();
    unsigned start = base[b], n = total[b];
    for (unsigned e = start + tid; e < start + n; e += 256) {
        unsigned u = sorted[e];
        atomicAdd(&acc[u & (BSIZE - 1)],
                  __uint_as_float(u & ~(unsigned)(BSIZE - 1)));
    }
    __syncthreads();
    int node0 = b << BSHIFT;
    for (int l = tid; l < BSIZE; l += 256) {
        int i = node0 + l;
        if (i < n_nodes)
            out[i] = (-v[i] + acc[l] + stim[i] + vrest[i]) / tau[i];
    }
}

// ---------------- fallback (agent-scope atomics, always correct) ----------------

__global__ void node_pre_kernel(const float* __restrict__ v,
                                const int* __restrict__ ntype,
                                const float* __restrict__ tp,
                                float* __restrict__ g,
                                float* __restrict__ msg, int n) {
    int i = blockIdx.x * blockDim.x + threadIdx.x;
    if (i < n) {
        float x = v[i];
        x = x > 0.0f ? x : 0.0f;
        g[i] = x * tp[ntype[i]];
        msg[i] = 0.0f;
    }
}

__global__ void edge_scatter_kernel(const int* __restrict__ src,
                                    const int* __restrict__ dst,
                                    const float* __restrict__ w,
                                    const float* __restrict__ g,
                                    float* __restrict__ msg, int n_vec) {
    int i = blockIdx.x * blockDim.x + threadIdx.x;
    if (i < n_vec) {
        int4 s = ((const int4*)src)[i];
        int4 d = ((const int4*)dst)[i];
        float4 wv = ((const float4*)w)[i];
        atomicAdd(&msg[d.x], wv.x * g[s.x]);
        atomicAdd(&msg[d.y], wv.y * g[s.y]);
        atomicAdd(&msg[d.z], wv.z * g[s.z]);
        atomicAdd(&msg[d.w], wv.w * g[s.w]);
    }
}

__global__ void edge_scatter_tail(const int* __restrict__ src,
                                  const int* __restrict__ dst,
                                  const float* __restrict__ w,
                                  const float* __restrict__ g,
                                  float* __restrict__ msg,
                                  int start, int n_edges) {
    int i = start + blockIdx.x * blockDim.x + threadIdx.x;
    if (i < n_edges) atomicAdd(&msg[dst[i]], w[i] * g[src[i]]);
}

__global__ void node_post_kernel(const float* __restrict__ v,
                                 const float* __restrict__ msg,
                                 const float* __restrict__ stim,
                                 const float* __restrict__ vrest,
                                 const float* __restrict__ tau,
                                 float* __restrict__ out, int n) {
    int i = blockIdx.x * blockDim.x + threadIdx.x;
    if (i < n)
        out[i] = (-v[i] + msg[i] + stim[i] + vrest[i]) / tau[i];
}

// ---------------- launch ----------------

extern "C" void kernel_launch(void* const* d_in, const int* in_sizes, int n_in,
                              void* d_out, int out_size, void* d_ws, size_t ws_size,
                              hipStream_t stream) {
    const float* voltage  = (const float*)d_in[0];
    const float* stimulus = (const float*)d_in[1];
    const int*   ntype    = (const int*)d_in[2];
    const int*   edge_idx = (const int*)d_in[3];
    const float* w        = (const float*)d_in[4];
    const float* vrest    = (const float*)d_in[5];
    const float* tau      = (const float*)d_in[6];
    const float* tp       = (const float*)d_in[7];
    float* out = (float*)d_out;

    const int n_nodes = in_sizes[0];
    const int n_edges = in_sizes[4];
    const int* src = edge_idx;
    const int* dst = edge_idx + n_edges;

    const int B = 256;
    const int G = n_edges / 4;
    int nblk = (G + GPB - 1) / GPB;
    if (nblk < 1) nblk = 1;
    const int nb = (n_nodes + BSIZE - 1) / BSIZE;

    auto align256 = [](size_t x) { return (x + 255) & ~(size_t)255; };
    size_t g_off      = 0;
    size_t sorted_off = align256(g_off + (size_t)n_nodes * 4);
    size_t cnt_off    = align256(sorted_off + (size_t)n_edges * 4);
    size_t total_off  = align256(cnt_off + (size_t)nb * nblk * 4);
    size_t base_off   = align256(total_off + (size_t)nb * 4);
    size_t need       = align256(base_off + (size_t)nb * 4);

    if (nb <= NBMAX && ws_size >= need) {
        float*    g      = (float*)((char*)d_ws + g_off);
        unsigned* sorted = (unsigned*)((char*)d_ws + sorted_off);
        unsigned* cnt    = (unsigned*)((char*)d_ws + cnt_off);
        unsigned* total  = (unsigned*)((char*)d_ws + total_off);
        unsigned* basep  = (unsigned*)((char*)d_ws + base_off);

        pre_g_kernel<<<(n_nodes + B - 1) / B, B, 0, stream>>>(
            voltage, ntype, tp, g, n_nodes);
        hist_kernel<<<nblk, B, 0, stream>>>(dst, cnt, G, n_edges, nblk, nb);
        scan_blocks_kernel<<<nb, B, 0, stream>>>(cnt, total, nblk);
        scan_buckets_kernel<<<1, B, 0, stream>>>(total, basep, nb);
        scatter_kernel<<<nblk, B, 0, stream>>>(src, dst, w, g, basep, cnt,
                                               sorted, G, n_edges, nblk, nb);
        accum_kernel<<<nb, B, 0, stream>>>(sorted, basep, total, voltage,
                                           stimulus, vrest, tau, out, n_nodes);
    } else {
        float* g   = (float*)d_ws;
        float* msg = (float*)d_ws + n_nodes;
        node_pre_kernel<<<(n_nodes + B - 1) / B, B, 0, stream>>>(
            voltage, ntype, tp, g, msg, n_nodes);
        if (G > 0)
            edge_scatter_kernel<<<(G + B - 1) / B, B, 0, stream>>>(
                src, dst, w, g, msg, G);
        if (G * 4 < n_edges) {
            int rem = n_edges - G * 4;
            edge_scatter_tail<<<(rem + B - 1) / B, B, 0, stream>>>(
                src, dst, w, g, msg, G * 4, n_edges);
        }
        node_post_kernel<<<(n_nodes + B - 1) / B, B, 0, stream>>>(
            voltage, msg, stimulus, vrest, tau, out, n_nodes);
    }
}

// Round 5
// 474.480 us; speedup vs baseline: 2.0064x; 1.0984x over previous
//
#include <hip/hip_runtime.h>

// dv = (-v + segment_sum(w * relu(v[src]) * tp[ntype[src]], dst) + stim + Vrest) / tau
// N_NODES = 500000, N_EDGES = 16000000. edge_index flat: src=[0,E), dst=[E,2E).
//
// R1: agent-scope fp32 atomics -> memory-side RMW wall (~20G/s) -> 785us.
// R2: counting sort, direct 4B random writes -> 7x write amp -> 489us scatter.
// R3: workgroup-scope atomics == agent-scope on gfx950 (no relocation).
// R4: LDS-staged bucket sort + coalesced burst copy-out -> 241us scatter, but
//     19% occupancy (73KB LDS, 256 thr -> 8 waves/CU) = latency-bound on the
//     16M random g[] gathers; dst read 3x (hist + scatter pass1 + pass2).
// R5 (this): scatter derives its local histogram from the scanned cnt matrix
//     (pass-1 deleted, dst read once); cnt stored blk-major so both hist
//     writes and scatter reads are coalesced; scatter uses 1024-thread blocks
//     -> 2 blocks/CU = 32 waves/CU (full occupancy) at the same LDS footprint.

#define BSHIFT 9
#define BSIZE  512               // nodes per bucket
#define NBMAX  1024              // >= nb = ceil(500000/512) = 977
#define GPB    4096              // int4 groups per scatter block = 16384 edges
#define EPB    (GPB * 4)

// ---------------- main path ----------------

__global__ void pre_g_kernel(const float* __restrict__ v,
                             const int* __restrict__ ntype,
                             const float* __restrict__ tp,
                             float* __restrict__ g, int n) {
    int i = blockIdx.x * blockDim.x + threadIdx.x;
    if (i < n) {
        float x = v[i];
        x = x > 0.0f ? x : 0.0f;
        g[i] = x * tp[ntype[i]];
    }
}

// cnt is blk-major: cnt[blk * nb + b] = #edges of block blk hitting bucket b.
__global__ void hist_kernel(const int* __restrict__ dst,
                            unsigned* __restrict__ cnt,
                            int G, int n_edges, int nblk, int nb) {
    __shared__ unsigned hist[NBMAX];
    int blk = blockIdx.x, tid = threadIdx.x;
    for (int i = tid; i < NBMAX; i += 512) hist[i] = 0;
    __syncthreads();
    const int4* d4 = (const int4*)dst;
    int gstart = blk * GPB;
    int gend = gstart + GPB; if (gend > G) gend = G;
    for (int i = gstart + tid; i < gend; i += 512) {
        int4 d = d4[i];
        atomicAdd(&hist[((unsigned)d.x) >> BSHIFT], 1u);
        atomicAdd(&hist[((unsigned)d.y) >> BSHIFT], 1u);
        atomicAdd(&hist[((unsigned)d.z) >> BSHIFT], 1u);
        atomicAdd(&hist[((unsigned)d.w) >> BSHIFT], 1u);
    }
    if (blk == nblk - 1) {
        for (int i = G * 4 + tid; i < n_edges; i += 512)
            atomicAdd(&hist[((unsigned)dst[i]) >> BSHIFT], 1u);
    }
    __syncthreads();
    for (int b = tid; b < nb; b += 512)
        cnt[(size_t)blk * nb + b] = hist[b];       // coalesced row write
}

// grid = nb; column b of blk-major cnt -> exclusive prefix across blocks
// (in place), total[b] = column sum.
__global__ void scan_blocks_kernel(unsigned* __restrict__ cnt,
                                   unsigned* __restrict__ total,
                                   int nblk, int nb) {
    __shared__ unsigned buf[256];
    __shared__ unsigned carry;
    int b = blockIdx.x, tid = threadIdx.x;
    if (tid == 0) carry = 0;
    __syncthreads();
    for (int i0 = 0; i0 < nblk; i0 += 256) {
        int i = i0 + tid;
        unsigned v = (i < nblk) ? cnt[(size_t)i * nb + b] : 0u;
        buf[tid] = v;
        __syncthreads();
        for (int o = 1; o < 256; o <<= 1) {
            unsigned t = (tid >= o) ? buf[tid - o] : 0u;
            __syncthreads();
            buf[tid] += t;
            __syncthreads();
        }
        unsigned excl = buf[tid] - v;
        if (i < nblk) cnt[(size_t)i * nb + b] = carry + excl;
        __syncthreads();
        if (tid == 255) carry += buf[255];
        __syncthreads();
    }
    if (tid == 0) total[b] = carry;
}

// single block: exclusive scan of total[0..nb) -> base[0..nb)
__global__ void scan_buckets_kernel(const unsigned* __restrict__ total,
                                    unsigned* __restrict__ base, int nb) {
    __shared__ unsigned buf[256];
    int tid = threadIdx.x;
    unsigned v[4];
    unsigned s = 0;
    for (int k = 0; k < 4; k++) {
        int i = tid * 4 + k;
        v[k] = (i < nb) ? total[i] : 0u;
        s += v[k];
    }
    buf[tid] = s;
    __syncthreads();
    for (int o = 1; o < 256; o <<= 1) {
        unsigned t = (tid >= o) ? buf[tid - o] : 0u;
        __syncthreads();
        buf[tid] += t;
        __syncthreads();
    }
    unsigned run = buf[tid] - s;
    for (int k = 0; k < 4; k++) {
        int i = tid * 4 + k;
        if (i < nb) base[i] = run;
        run += v[k];
    }
}

// grid = nblk, 1024 threads. Local histogram is recovered from the scanned
// cnt matrix (prefix differences) -- no pass over dst needed for it.
// Bin 16K packed records into bucket-ordered LDS, then copy each bucket
// segment out as a coalesced burst to its prefix-assigned global slice.
__global__ __launch_bounds__(1024, 8)
void scatter_kernel(const int* __restrict__ src,
                    const int* __restrict__ dst,
                    const float* __restrict__ w,
                    const float* __restrict__ g,
                    const unsigned* __restrict__ base,
                    const unsigned* __restrict__ cnt,   // scanned, blk-major
                    const unsigned* __restrict__ total,
                    unsigned* __restrict__ sorted,
                    int G, int n_edges, int nblk, int nb) {
    __shared__ unsigned stage[EPB];      // 64 KB
    __shared__ unsigned lcur[NBMAX];     // excl starts -> ends (4 KB)
    __shared__ unsigned gseg[NBMAX];     // global segment start (4 KB)
    int blk = blockIdx.x, tid = threadIdx.x;
    bool last = (blk == nblk - 1);

    // per-bucket count for this block from prefix differences + global start
    unsigned cntv = 0;
    if (tid < nb) {
        unsigned pref = cnt[(size_t)blk * nb + tid];             // coalesced
        unsigned nxt  = (blk + 1 < nblk) ? cnt[(size_t)(blk + 1) * nb + tid]
                                         : total[tid];
        cntv = nxt - pref;
        gseg[tid] = base[tid] + pref;
    }
    lcur[tid] = cntv;
    __syncthreads();
    // in-place Hillis-Steele inclusive scan over 1024 entries
    for (int o = 1; o < 1024; o <<= 1) {
        unsigned t = (tid >= o) ? lcur[tid - o] : 0u;
        __syncthreads();
        lcur[tid] += t;
        __syncthreads();
    }
    lcur[tid] -= cntv;                   // exclusive start (own slot)
    __syncthreads();

    // bin packed records (value mantissa-high | local dst) into LDS
    const int4*   s4 = (const int4*)src;
    const int4*   d4 = (const int4*)dst;
    const float4* w4 = (const float4*)w;
    int gstart = blk * GPB;
    int gend = gstart + GPB; if (gend > G) gend = G;
    for (int i = gstart + tid; i < gend; i += 1024) {
        int4 s = s4[i]; int4 d = d4[i]; float4 wv = w4[i];
        {
            unsigned b = ((unsigned)d.x) >> BSHIFT;
            unsigned pos = atomicAdd(&lcur[b], 1u);
            stage[pos] = (__float_as_uint(wv.x * g[s.x]) & ~(unsigned)(BSIZE - 1)) |
                         ((unsigned)d.x & (BSIZE - 1));
        }
        {
            unsigned b = ((unsigned)d.y) >> BSHIFT;
            unsigned pos = atomicAdd(&lcur[b], 1u);
            stage[pos] = (__float_as_uint(wv.y * g[s.y]) & ~(unsigned)(BSIZE - 1)) |
                         ((unsigned)d.y & (BSIZE - 1));
        }
        {
            unsigned b = ((unsigned)d.z) >> BSHIFT;
            unsigned pos = atomicAdd(&lcur[b], 1u);
            stage[pos] = (__float_as_uint(wv.z * g[s.z]) & ~(unsigned)(BSIZE - 1)) |
                         ((unsigned)d.z & (BSIZE - 1));
        }
        {
            unsigned b = ((unsigned)d.w) >> BSHIFT;
            unsigned pos = atomicAdd(&lcur[b], 1u);
            stage[pos] = (__float_as_uint(wv.w * g[s.w]) & ~(unsigned)(BSIZE - 1)) |
                         ((unsigned)d.w & (BSIZE - 1));
        }
    }
    if (last) {
        for (int i = G * 4 + tid; i < n_edges; i += 1024) {
            int dd = dst[i];
            unsigned b = ((unsigned)dd) >> BSHIFT;
            unsigned pos = atomicAdd(&lcur[b], 1u);
            stage[pos] = (__float_as_uint(w[i] * g[src[i]]) & ~(unsigned)(BSIZE - 1)) |
                         ((unsigned)dd & (BSIZE - 1));
        }
    }
    __syncthreads();

    // copy-out: one wave per bucket segment, coalesced burst.
    // lcur[b] is now segment end; start = (b ? lcur[b-1] : 0).
    int wave = tid >> 6, lane = tid & 63;
    for (int b = wave; b < nb; b += 16) {
        unsigned lend = lcur[b];
        unsigned lstart = (b == 0) ? 0u : lcur[b - 1];
        unsigned gs = gseg[b];
        for (unsigned j = lane; j < lend - lstart; j += 64)
            sorted[gs + j] = stage[lstart + j];
    }
}

// grid = nb, 512 threads; accumulate one bucket (contiguous records) in LDS.
__global__ void accum_kernel(const unsigned* __restrict__ sorted,
                             const unsigned* __restrict__ base,
                             const unsigned* __restrict__ total,
                             const float* __restrict__ v,
                             const float* __restrict__ stim,
                             const float* __restrict__ vrest,
                             const float* __restrict__ tau,
                             float* __restrict__ out,
                             int n_nodes) {
    __shared__ float acc[BSIZE];
    int b = blockIdx.x, tid = threadIdx.x;
    acc[tid] = 0.0f;
    __syncthreads();
    unsigned start = base[b], n = total[b];
    for (unsigned e = start + tid; e < start + n; e += 512) {
        unsigned u = sorted[e];
        atomicAdd(&acc[u & (BSIZE - 1)],
                  __uint_as_float(u & ~(unsigned)(BSIZE - 1)));
    }
    __syncthreads();
    int i = (b << BSHIFT) + tid;
    if (i < n_nodes)
        out[i] = (-v[i] + acc[tid] + stim[i] + vrest[i]) / tau[i];
}

// ---------------- fallback (agent-scope atomics, always correct) ----------------

__global__ void node_pre_kernel(const float* __restrict__ v,
                                const int* __restrict__ ntype,
                                const float* __restrict__ tp,
                                float* __restrict__ g,
                                float* __restrict__ msg, int n) {
    int i = blockIdx.x * blockDim.x + threadIdx.x;
    if (i < n) {
        float x = v[i];
        x = x > 0.0f ? x : 0.0f;
        g[i] = x * tp[ntype[i]];
        msg[i] = 0.0f;
    }
}

__global__ void edge_scatter_kernel(const int* __restrict__ src,
                                    const int* __restrict__ dst,
                                    const float* __restrict__ w,
                                    const float* __restrict__ g,
                                    float* __restrict__ msg, int n_vec) {
    int i = blockIdx.x * blockDim.x + threadIdx.x;
    if (i < n_vec) {
        int4 s = ((const int4*)src)[i];
        int4 d = ((const int4*)dst)[i];
        float4 wv = ((const float4*)w)[i];
        atomicAdd(&msg[d.x], wv.x * g[s.x]);
        atomicAdd(&msg[d.y], wv.y * g[s.y]);
        atomicAdd(&msg[d.z], wv.z * g[s.z]);
        atomicAdd(&msg[d.w], wv.w * g[s.w]);
    }
}

__global__ void edge_scatter_tail(const int* __restrict__ src,
                                  const int* __restrict__ dst,
                                  const float* __restrict__ w,
                                  const float* __restrict__ g,
                                  float* __restrict__ msg,
                                  int start, int n_edges) {
    int i = start + blockIdx.x * blockDim.x + threadIdx.x;
    if (i < n_edges) atomicAdd(&msg[dst[i]], w[i] * g[src[i]]);
}

__global__ void node_post_kernel(const float* __restrict__ v,
                                 const float* __restrict__ msg,
                                 const float* __restrict__ stim,
                                 const float* __restrict__ vrest,
                                 const float* __restrict__ tau,
                                 float* __restrict__ out, int n) {
    int i = blockIdx.x * blockDim.x + threadIdx.x;
    if (i < n)
        out[i] = (-v[i] + msg[i] + stim[i] + vrest[i]) / tau[i];
}

// ---------------- launch ----------------

extern "C" void kernel_launch(void* const* d_in, const int* in_sizes, int n_in,
                              void* d_out, int out_size, void* d_ws, size_t ws_size,
                              hipStream_t stream) {
    const float* voltage  = (const float*)d_in[0];
    const float* stimulus = (const float*)d_in[1];
    const int*   ntype    = (const int*)d_in[2];
    const int*   edge_idx = (const int*)d_in[3];
    const float* w        = (const float*)d_in[4];
    const float* vrest    = (const float*)d_in[5];
    const float* tau      = (const float*)d_in[6];
    const float* tp       = (const float*)d_in[7];
    float* out = (float*)d_out;

    const int n_nodes = in_sizes[0];
    const int n_edges = in_sizes[4];
    const int* src = edge_idx;
    const int* dst = edge_idx + n_edges;

    const int B = 256;
    const int G = n_edges / 4;
    int nblk = (G + GPB - 1) / GPB;
    if (nblk < 1) nblk = 1;
    const int nb = (n_nodes + BSIZE - 1) / BSIZE;

    auto align256 = [](size_t x) { return (x + 255) & ~(size_t)255; };
    size_t g_off      = 0;
    size_t sorted_off = align256(g_off + (size_t)n_nodes * 4);
    size_t cnt_off    = align256(sorted_off + (size_t)n_edges * 4);
    size_t total_off  = align256(cnt_off + (size_t)nb * nblk * 4);
    size_t base_off   = align256(total_off + (size_t)nb * 4);
    size_t need       = align256(base_off + (size_t)nb * 4);

    if (nb <= NBMAX && ws_size >= need) {
        float*    g      = (float*)((char*)d_ws + g_off);
        unsigned* sorted = (unsigned*)((char*)d_ws + sorted_off);
        unsigned* cnt    = (unsigned*)((char*)d_ws + cnt_off);
        unsigned* total  = (unsigned*)((char*)d_ws + total_off);
        unsigned* basep  = (unsigned*)((char*)d_ws + base_off);

        pre_g_kernel<<<(n_nodes + B - 1) / B, B, 0, stream>>>(
            voltage, ntype, tp, g, n_nodes);
        hist_kernel<<<nblk, 512, 0, stream>>>(dst, cnt, G, n_edges, nblk, nb);
        scan_blocks_kernel<<<nb, 256, 0, stream>>>(cnt, total, nblk, nb);
        scan_buckets_kernel<<<1, 256, 0, stream>>>(total, basep, nb);
        scatter_kernel<<<nblk, 1024, 0, stream>>>(src, dst, w, g, basep, cnt,
                                                  total, sorted, G, n_edges,
                                                  nblk, nb);
        accum_kernel<<<nb, 512, 0, stream>>>(sorted, basep, total, voltage,
                                             stimulus, vrest, tau, out, n_nodes);
    } else {
        float* g   = (float*)d_ws;
        float* msg = (float*)d_ws + n_nodes;
        node_pre_kernel<<<(n_nodes + B - 1) / B, B, 0, stream>>>(
            voltage, ntype, tp, g, msg, n_nodes);
        if (G > 0)
            edge_scatter_kernel<<<(G + B - 1) / B, B, 0, stream>>>(
                src, dst, w, g, msg, G);
        if (G * 4 < n_edges) {
            int rem = n_edges - G * 4;
            edge_scatter_tail<<<(rem + B - 1) / B, B, 0, stream>>>(
                src, dst, w, g, msg, G * 4, n_edges);
        }
        node_post_kernel<<<(n_nodes + B - 1) / B, B, 0, stream>>>(
            voltage, msg, stimulus, vrest, tau, out, n_nodes);
    }
}